// Round 1
// baseline (3002.180 us; speedup 1.0000x reference)
//
#include <hip/hip_runtime.h>
#include <hip/hip_bf16.h>
#include <math.h>

// Problem constants
constexpr int kB  = 8;
constexpr int kT  = 1024;
constexpr int kC  = 768;
constexpr int kNH = 12;
constexpr int kHD = 64;
constexpr int kM  = kB * kT;        // 8192 rows
constexpr int k3C = 3 * kC;         // 2304
constexpr int k4C = 4 * kC;         // 3072

// ---------------------------------------------------------------------------
// LayerNorm: one block (256 threads) per row of 768.
// ---------------------------------------------------------------------------
__global__ __launch_bounds__(256) void ln_kernel(
    const float* __restrict__ x, const float* __restrict__ g,
    const float* __restrict__ bta, float* __restrict__ out)
{
  __shared__ float red[4];
  int row = blockIdx.x;
  int tid = threadIdx.x;
  const float* xr = x + (size_t)row * kC;
  float v0 = xr[tid], v1 = xr[tid + 256], v2 = xr[tid + 512];

  float s = v0 + v1 + v2;
#pragma unroll
  for (int off = 32; off; off >>= 1) s += __shfl_xor(s, off);
  if ((tid & 63) == 0) red[tid >> 6] = s;
  __syncthreads();
  float mu = (red[0] + red[1] + red[2] + red[3]) * (1.0f / kC);

  float d0 = v0 - mu, d1 = v1 - mu, d2 = v2 - mu;
  float q = d0 * d0 + d1 * d1 + d2 * d2;
#pragma unroll
  for (int off = 32; off; off >>= 1) q += __shfl_xor(q, off);
  __syncthreads();          // guard red[] reuse
  if ((tid & 63) == 0) red[tid >> 6] = q;
  __syncthreads();
  float var = (red[0] + red[1] + red[2] + red[3]) * (1.0f / kC);
  float inv = rsqrtf(var + 1e-5f);

  float* orow = out + (size_t)row * kC;
  orow[tid]       = d0 * inv * g[tid]       + bta[tid];
  orow[tid + 256] = d1 * inv * g[tid + 256] + bta[tid + 256];
  orow[tid + 512] = d2 * inv * g[tid + 512] + bta[tid + 512];
}

// ---------------------------------------------------------------------------
// fp32 GEMM: out[M,N] = A[M,K] @ W[K,N] + bias (+R) (GELU optional)
// 128x128 tile, BK=16, 256 threads, 8x8 microtile.
// ---------------------------------------------------------------------------
__device__ inline float gelu_tanh(float c) {
  float t = 0.7978845608028654f * (c + 0.044715f * c * c * c);
  return 0.5f * c * (1.0f + tanhf(t));
}

template <bool GELU, bool RES>
__global__ __launch_bounds__(256) void gemm_kernel(
    const float* __restrict__ A, const float* __restrict__ W,
    const float* __restrict__ bias, const float* __restrict__ R,
    float* __restrict__ out, int M, int N, int K)
{
  constexpr int BM = 128, BN = 128, BK = 16, PAD = 132; // PAD%4==0 (16B align), PAD%32==4
  __shared__ float As[BK][PAD];   // stored transposed: As[k][m]
  __shared__ float Bs[BK][PAD];   // Bs[k][n]
  int tid = threadIdx.x;
  int m0 = blockIdx.y * BM, n0 = blockIdx.x * BN;
  int ty = tid >> 4, tx = tid & 15;

  int ar = tid >> 1, ak = (tid & 1) * 8;   // A load: 128 rows x 16 k
  int br = tid >> 4, bn = (tid & 15) * 8;  // B load: 16 k x 128 n
  const float* Ap = A + (size_t)(m0 + ar) * K + ak;
  const float* Wp = W + (size_t)br * N + n0 + bn;

  float acc[8][8] = {};

  for (int k0 = 0; k0 < K; k0 += BK) {
    float4 a0 = *(const float4*)(Ap + k0);
    float4 a1 = *(const float4*)(Ap + k0 + 4);
    float4 w0 = *(const float4*)(Wp + (size_t)k0 * N);
    float4 w1 = *(const float4*)(Wp + (size_t)k0 * N + 4);
    __syncthreads();   // previous tile fully consumed
    As[ak + 0][ar] = a0.x; As[ak + 1][ar] = a0.y;
    As[ak + 2][ar] = a0.z; As[ak + 3][ar] = a0.w;
    As[ak + 4][ar] = a1.x; As[ak + 5][ar] = a1.y;
    As[ak + 6][ar] = a1.z; As[ak + 7][ar] = a1.w;
    *(float4*)&Bs[br][bn]     = w0;
    *(float4*)&Bs[br][bn + 4] = w1;
    __syncthreads();
#pragma unroll
    for (int kk = 0; kk < BK; ++kk) {
      float4 x0 = *(const float4*)&As[kk][ty * 8];
      float4 x1 = *(const float4*)&As[kk][ty * 8 + 4];
      float4 y0 = *(const float4*)&Bs[kk][tx * 8];
      float4 y1 = *(const float4*)&Bs[kk][tx * 8 + 4];
      float a8[8] = {x0.x, x0.y, x0.z, x0.w, x1.x, x1.y, x1.z, x1.w};
      float b8[8] = {y0.x, y0.y, y0.z, y0.w, y1.x, y1.y, y1.z, y1.w};
#pragma unroll
      for (int i = 0; i < 8; ++i)
#pragma unroll
        for (int j = 0; j < 8; ++j)
          acc[i][j] = fmaf(a8[i], b8[j], acc[i][j]);
    }
  }

#pragma unroll
  for (int i = 0; i < 8; ++i) {
    int m = m0 + ty * 8 + i;
#pragma unroll
    for (int j = 0; j < 8; ++j) {
      int n = n0 + tx * 8 + j;
      float c = acc[i][j] + bias[n];
      if (RES) c += R[(size_t)m * N + n];
      if (GELU) c = gelu_tanh(c);
      out[(size_t)m * N + n] = c;
    }
  }
}

// ---------------------------------------------------------------------------
// Attention: one block per (b, h, 4 q-rows); 4 waves, 1 wave per q-row.
// K/V tiles (64 keys x 64 dims) staged in LDS; full score row in regs+LDS.
// ---------------------------------------------------------------------------
__global__ __launch_bounds__(256) void attn_kernel(
    const float* __restrict__ qkv, const int* __restrict__ mask,
    float* __restrict__ o)
{
  constexpr int PAD = kHD + 1;  // 65: (lane*65+d)%32=(lane+d)%32 -> 2-way, free
  __shared__ float q_s[4][kHD];
  __shared__ float p_s[4][kT];
  __shared__ float tile[64][PAD];

  int b = blockIdx.z, h = blockIdx.y, q0 = blockIdx.x * 4;
  int tid = threadIdx.x, w = tid >> 6, lane = tid & 63;
  const size_t rs = k3C;  // qkv row stride
  const float* qb = qkv + (size_t)b * kT * rs + h * kHD;
  const float* kb = qb + kC;
  const float* vb = qb + 2 * kC;

  // stage the 4 q rows
  q_s[tid >> 6][tid & 63] = qb[(size_t)(q0 + (tid >> 6)) * rs + (tid & 63)];
  __syncthreads();

  float s_reg[16];
  // phase 1: scores. key for (t, lane) = t*64 + lane
  for (int t = 0; t < 16; ++t) {
    __syncthreads();
#pragma unroll
    for (int i = 0; i < 4; ++i) {
      int idx = tid + i * 256;          // 0..1023
      int r = idx >> 4, d4 = (idx & 15) * 4;
      float4 kv4 = *(const float4*)(kb + (size_t)(t * 64 + r) * rs + d4);
      tile[r][d4 + 0] = kv4.x; tile[r][d4 + 1] = kv4.y;
      tile[r][d4 + 2] = kv4.z; tile[r][d4 + 3] = kv4.w;
    }
    __syncthreads();
    float s = 0.f;
#pragma unroll
    for (int d = 0; d < kHD; ++d) s = fmaf(q_s[w][d], tile[lane][d], s);
    s_reg[t] = s;
  }

  // phase 2: mask + softmax (per-wave, register + shuffle)
  float mx = -INFINITY;
#pragma unroll
  for (int t = 0; t < 16; ++t) {
    int key = t * 64 + lane;
    float sv = (mask[b * kT + key] != 0) ? s_reg[t] * 0.125f : -INFINITY;
    s_reg[t] = sv;
    mx = fmaxf(mx, sv);
  }
#pragma unroll
  for (int off = 32; off; off >>= 1) mx = fmaxf(mx, __shfl_xor(mx, off));
  float sum = 0.f;
#pragma unroll
  for (int t = 0; t < 16; ++t) { float p = expf(s_reg[t] - mx); s_reg[t] = p; sum += p; }
#pragma unroll
  for (int off = 32; off; off >>= 1) sum += __shfl_xor(sum, off);
  float isum = 1.f / sum;
#pragma unroll
  for (int t = 0; t < 16; ++t) p_s[w][t * 64 + lane] = s_reg[t] * isum;

  // phase 3: o = P @ V ; lane owns output dim d = lane
  float acc = 0.f;
  for (int t = 0; t < 16; ++t) {
    __syncthreads();
#pragma unroll
    for (int i = 0; i < 4; ++i) {
      int idx = tid + i * 256;
      int r = idx >> 4, d4 = (idx & 15) * 4;
      float4 vv = *(const float4*)(vb + (size_t)(t * 64 + r) * rs + d4);
      tile[r][d4 + 0] = vv.x; tile[r][d4 + 1] = vv.y;
      tile[r][d4 + 2] = vv.z; tile[r][d4 + 3] = vv.w;
    }
    __syncthreads();
#pragma unroll
    for (int kk = 0; kk < 64; ++kk)
      acc = fmaf(p_s[w][t * 64 + kk], tile[kk][lane], acc);
  }
  o[((size_t)(b * kT) + q0 + w) * kC + h * kHD + lane] = acc;
}

// ---------------------------------------------------------------------------
// Launch
// ---------------------------------------------------------------------------
extern "C" void kernel_launch(void* const* d_in, const int* in_sizes, int n_in,
                              void* d_out, int out_size, void* d_ws, size_t ws_size,
                              hipStream_t stream) {
  const float* x      = (const float*)d_in[0];
  const int*   amask  = (const int*)  d_in[1];
  const float* ln1_g  = (const float*)d_in[2];
  const float* ln1_b  = (const float*)d_in[3];
  const float* W_attn = (const float*)d_in[4];
  const float* b_attn = (const float*)d_in[5];
  const float* W_proj = (const float*)d_in[6];
  const float* b_proj = (const float*)d_in[7];
  const float* ln2_g  = (const float*)d_in[8];
  const float* ln2_b  = (const float*)d_in[9];
  const float* W_fc   = (const float*)d_in[10];
  const float* b_fc   = (const float*)d_in[11];
  const float* W_fc2  = (const float*)d_in[12];
  const float* b_fc2  = (const float*)d_in[13];
  float* out = (float*)d_out;

  // workspace layout (bytes):
  //   [0, 25165824)           h / o / h2   (each dead before next user)
  //   [25165824, 100663296)   qkv          (dead after attention)
  //   [25165824, 125829120)   fc           (overlays dead qkv)
  // x1 lives in d_out (written by proj GEMM, consumed in-place by final GEMM).
  char* ws = (char*)d_ws;
  float* h_buf = (float*)(ws);
  float* qkv_b = (float*)(ws + 25165824);
  float* fc_b  = (float*)(ws + 25165824);

  dim3 blk(256);

  // 1. h = LN1(x)
  ln_kernel<<<kM, blk, 0, stream>>>(x, ln1_g, ln1_b, h_buf);
  // 2. qkv = h @ W_attn + b_attn
  gemm_kernel<false, false><<<dim3(k3C / 128, kM / 128), blk, 0, stream>>>(
      h_buf, W_attn, b_attn, nullptr, qkv_b, kM, k3C, kC);
  // 3. o = attention(qkv, mask)   (o overwrites h)
  attn_kernel<<<dim3(kT / 4, kNH, kB), blk, 0, stream>>>(qkv_b, amask, h_buf);
  // 4. x1 = x + o @ W_proj + b_proj   -> d_out
  gemm_kernel<false, true><<<dim3(kC / 128, kM / 128), blk, 0, stream>>>(
      h_buf, W_proj, b_proj, x, out, kM, kC, kC);
  // 5. h2 = LN2(x1)
  ln_kernel<<<kM, blk, 0, stream>>>(out, ln2_g, ln2_b, h_buf);
  // 6. fc = gelu(h2 @ W_fc + b_fc)
  gemm_kernel<true, false><<<dim3(k4C / 128, kM / 128), blk, 0, stream>>>(
      h_buf, W_fc, b_fc, nullptr, fc_b, kM, k4C, kC);
  // 7. out = x1 + fc @ W_fc2 + b_fc2  (in-place residual on d_out)
  gemm_kernel<false, true><<<dim3(kC / 128, kM / 128), blk, 0, stream>>>(
      fc_b, W_fc2, b_fc2, out, out, kM, kC, k4C);
}